// Round 2
// baseline (1098.612 us; speedup 1.0000x reference)
//
#include <hip/hip_runtime.h>

// Problem constants (from reference)
#define TV_ 2048
#define NB_ 16
#define NV_ 1024
#define TK_ 2048
#define NK_ 1024

typedef float  f32x4 __attribute__((ext_vector_type(4)));
typedef float  fl4   __attribute__((ext_vector_type(4)));
typedef __bf16 bfx8  __attribute__((ext_vector_type(8)));

static __device__ __forceinline__ ushort f2bf(float f){
  unsigned u = __builtin_bit_cast(unsigned, f);
  u += 0x7FFFu + ((u >> 16) & 1u);          // RN-even
  return (ushort)(u >> 16);
}
static __device__ __forceinline__ float bf2f(ushort h){
  unsigned u = ((unsigned)h) << 16;
  return __builtin_bit_cast(float, u);
}

// ---------------- elementwise split: fp32 -> (hi,lo) bf16 pair ----------------
__global__ __launch_bounds__(256) void split_pair_k(const float* __restrict__ x,
                                                    ushort* __restrict__ hi,
                                                    ushort* __restrict__ lo, long n4){
  long i = (long)blockIdx.x*256 + threadIdx.x;
  const long stride = (long)gridDim.x*256;
  for (; i < n4; i += stride){
    fl4 v = ((const fl4*)x)[i];
    ushort h0=f2bf(v[0]), h1=f2bf(v[1]), h2=f2bf(v[2]), h3=f2bf(v[3]);
    ushort4 H = make_ushort4(h0,h1,h2,h3);
    ushort4 L = make_ushort4(f2bf(v[0]-bf2f(h0)), f2bf(v[1]-bf2f(h1)),
                             f2bf(v[2]-bf2f(h2)), f2bf(v[3]-bf2f(h3)));
    ((ushort4*)hi)[i] = H;
    ((ushort4*)lo)[i] = L;
  }
}

// ---------------- w [K,V] -> wT [V,K] (hi,lo) ----------------
__global__ void wtrans_k(const float* __restrict__ w,
                         ushort* __restrict__ hiT, ushort* __restrict__ loT){
  __shared__ float t[32][33];
  const int tx = threadIdx.x, ty = threadIdx.y;       // 32 x 8
  const int k0 = blockIdx.x*32, v0 = blockIdx.y*32;
#pragma unroll
  for (int r=0;r<4;++r) t[ty+8*r][tx] = w[(long)(k0+ty+8*r)*NV_ + v0+tx];
  __syncthreads();
#pragma unroll
  for (int r=0;r<4;++r){
    float x = t[tx][ty+8*r];
    long o = (long)(v0+ty+8*r)*NK_ + k0+tx;
    ushort h = f2bf(x);
    hiT[o] = h;
    loT[o] = f2bf(x - bf2f(h));
  }
}

// ------------- values [Tv,B,V] -> v2 [B,Tv,V] (hi,lo), pure permutation -------------
__global__ __launch_bounds__(256) void v2_build_k(const float* __restrict__ vals,
                                                  ushort* __restrict__ hi,
                                                  ushort* __restrict__ lo){
  const long n4 = (long)NB_*TV_*NV_/4;
  long i = (long)blockIdx.x*256 + threadIdx.x;
  const long stride = (long)gridDim.x*256;
  for (; i < n4; i += stride){
    const long o = i << 2;
    const int b = (int)(o >> 21);              // / (Tv*V) = 2^21
    const int s = (int)((o >> 10) & (TV_-1));
    const int v = (int)(o & (NV_-1));
    fl4 val = *(const fl4*)(vals + ((long)s*NB_ + b)*NV_ + v);
    ushort h0=f2bf(val[0]), h1=f2bf(val[1]), h2=f2bf(val[2]), h3=f2bf(val[3]);
    *(ushort4*)(hi + o) = make_ushort4(h0,h1,h2,h3);
    *(ushort4*)(lo + o) = make_ushort4(f2bf(val[0]-bf2f(h0)), f2bf(val[1]-bf2f(h1)),
                                       f2bf(val[2]-bf2f(h2)), f2bf(val[3]-bf2f(h3)));
  }
}

// ------------- values [Tv,B,V] -> vbt [B,V,Tv] bf16 (hi only), tiled transpose -------------
__global__ void vbt_build_k(const float* __restrict__ vals, ushort* __restrict__ out){
  __shared__ float t[32][33];
  const int tx = threadIdx.x, ty = threadIdx.y;       // 32 x 8
  const int s0 = blockIdx.x*32, v0 = blockIdx.y*32, b = blockIdx.z;
#pragma unroll
  for (int r=0;r<4;++r)
    t[ty+8*r][tx] = vals[((long)(s0+ty+8*r)*NB_ + b)*NV_ + v0+tx];
  __syncthreads();
#pragma unroll
  for (int r=0;r<4;++r)
    out[((long)b*NV_ + v0+ty+8*r)*TV_ + s0+tx] = f2bf(t[tx][ty+8*r]);
}

// ---------------- GEMM: C[M,N] (+batch) = A[M,K] * BT[N,K]^T ----------------
// bf16 MFMA 16x16x32, 128x128 tile, BK=64, 4 waves, global_load_lds staging,
// XOR swizzle (16B slot ^ (row&7)) applied on the *source* address (linear LDS dest)
// and unwound at ds_read time.
static __device__ __forceinline__ void stage_tile(const ushort* __restrict__ src, int ldk,
                                                  ushort* dst, int w, int lane){
#pragma unroll
  for (int c=0;c<4;++c){
    const int chunk0 = (w<<8) + (c<<6);       // wave-uniform 16B-chunk base
    const int idx = chunk0 + lane;            // this lane's chunk
    const int row = idx >> 3;                 // 8 chunks (128B) per row
    const int sl  = idx & 7;
    const ushort* g = src + (long)row*ldk + ((sl ^ (row & 7)) << 3);
    __builtin_amdgcn_global_load_lds((const __attribute__((address_space(1))) unsigned int*)g,
                                     (__attribute__((address_space(3))) unsigned int*)(dst + (long)chunk0*8),
                                     16, 0, 0);
  }
}

static __device__ __forceinline__ bfx8 ldfrag(const ushort* base, int r, int q){
  const int off = r*128 + (((q ^ (r & 7)) & 7) << 4);
  return *(const bfx8*)((const char*)base + off);
}

template<int NPASS, int OUTPAIR>
__global__ __launch_bounds__(256)
void gemm_bt_k(const ushort* __restrict__ Ah, const ushort* __restrict__ Al,
               const ushort* __restrict__ Bh, const ushort* __restrict__ Bl,
               float* __restrict__ C, ushort* __restrict__ Ch, ushort* __restrict__ Cl,
               int N, int K, long sA, long sB, long sC)
{
  __shared__ __align__(16) ushort sAh[128*64];
  __shared__ __align__(16) ushort sBh[128*64];
  __shared__ __align__(16) ushort sAl[(NPASS==3)?128*64:8];
  __shared__ __align__(16) ushort sBl[(NPASS==3)?128*64:8];

  const int tid  = threadIdx.x;
  const int lane = tid & 63;
  const int w    = tid >> 6;
  const int bz   = blockIdx.z;
  const int m0   = blockIdx.y * 128;
  const int n0   = blockIdx.x * 128;

  const ushort* Ahp = Ah + (long)bz*sA + (long)m0*K;
  const ushort* Bhp = Bh + (long)bz*sB + (long)n0*K;
  const ushort* Alp = (NPASS==3) ? (Al + (long)bz*sA + (long)m0*K) : Ah;
  const ushort* Blp = (NPASS==3) ? (Bl + (long)bz*sB + (long)n0*K) : Bh;

  f32x4 acc[4][4];
#pragma unroll
  for (int i=0;i<4;++i)
#pragma unroll
    for (int j=0;j<4;++j) acc[i][j] = (f32x4){0.f,0.f,0.f,0.f};

  const int wm = (w>>1)*64, wn = (w&1)*64;
  const int lm = lane & 15, lq = lane >> 4;

  for (int k0=0; k0<K; k0+=64){
    __syncthreads();                 // protect LDS from previous iter's readers
    stage_tile(Ahp + k0, K, sAh, w, lane);
    stage_tile(Bhp + k0, K, sBh, w, lane);
    if constexpr (NPASS==3){
      stage_tile(Alp + k0, K, sAl, w, lane);
      stage_tile(Blp + k0, K, sBl, w, lane);
    }
    __syncthreads();                 // compiler drains vmcnt(0) before barrier
#pragma unroll
    for (int kk=0; kk<2; ++kk){
      bfx8 ah[4], bh[4], al[4], bl[4];
#pragma unroll
      for (int i=0;i<4;++i){
        const int r = wm + i*16 + lm;
        ah[i] = ldfrag(sAh, r, lq + kk*4);
        if constexpr (NPASS==3) al[i] = ldfrag(sAl, r, lq + kk*4);
      }
#pragma unroll
      for (int j=0;j<4;++j){
        const int r = wn + j*16 + lm;
        bh[j] = ldfrag(sBh, r, lq + kk*4);
        if constexpr (NPASS==3) bl[j] = ldfrag(sBl, r, lq + kk*4);
      }
#pragma unroll
      for (int i=0;i<4;++i)
#pragma unroll
        for (int j=0;j<4;++j){
          acc[i][j] = __builtin_amdgcn_mfma_f32_16x16x32_bf16(ah[i], bh[j], acc[i][j], 0,0,0);
          if constexpr (NPASS==3){
            acc[i][j] = __builtin_amdgcn_mfma_f32_16x16x32_bf16(ah[i], bl[j], acc[i][j], 0,0,0);
            acc[i][j] = __builtin_amdgcn_mfma_f32_16x16x32_bf16(al[i], bh[j], acc[i][j], 0,0,0);
          }
        }
    }
  }

  const long cb = (long)bz*sC;
#pragma unroll
  for (int i=0;i<4;++i)
#pragma unroll
    for (int j=0;j<4;++j)
#pragma unroll
      for (int g=0; g<4; ++g){
        const int gm = m0 + wm + i*16 + lq*4 + g;   // C/D: row = 4*(lane>>4)+reg
        const int gn = n0 + wn + j*16 + lm;         //      col = lane&15
        const long o = cb + (long)gm*N + gn;
        const float v = acc[i][j][g];
        if constexpr (OUTPAIR){
          const ushort h = f2bf(v);
          Ch[o] = h;
          Cl[o] = f2bf(v - bf2f(h));
        } else {
          C[o] = v;
        }
      }
}

// ---------------- row softmax over Tv, in-place fp32 + bf16 copy ----------------
__global__ __launch_bounds__(256) void softmax_k(float* __restrict__ lg, ushort* __restrict__ pb){
  const long base = (long)blockIdx.x * TV_;
  const int tid = threadIdx.x;
  const int lane = tid & 63, w = tid >> 6;
  float x[8];
  fl4 a = *(const fl4*)(lg + base + tid*8);
  fl4 b = *(const fl4*)(lg + base + tid*8 + 4);
  x[0]=a[0];x[1]=a[1];x[2]=a[2];x[3]=a[3];x[4]=b[0];x[5]=b[1];x[6]=b[2];x[7]=b[3];
  float m = x[0];
#pragma unroll
  for (int j=1;j<8;++j) m = fmaxf(m, x[j]);
#pragma unroll
  for (int off=32; off; off>>=1) m = fmaxf(m, __shfl_xor(m, off));
  __shared__ float rm[4], rs[4];
  if (lane==0) rm[w]=m;
  __syncthreads();
  m = fmaxf(fmaxf(rm[0],rm[1]), fmaxf(rm[2],rm[3]));
  float s = 0.f;
#pragma unroll
  for (int j=0;j<8;++j){ x[j] = __expf(x[j]-m); s += x[j]; }
#pragma unroll
  for (int off=32; off; off>>=1) s += __shfl_xor(s, off);
  if (lane==0) rs[w]=s;
  __syncthreads();
  s = rs[0]+rs[1]+rs[2]+rs[3];
  const float inv = 1.f/s;
  fl4 p0 = {x[0]*inv, x[1]*inv, x[2]*inv, x[3]*inv};
  fl4 p1 = {x[4]*inv, x[5]*inv, x[6]*inv, x[7]*inv};
  *(fl4*)(lg + base + tid*8)     = p0;
  *(fl4*)(lg + base + tid*8 + 4) = p1;
  *(ushort4*)(pb + base + tid*8)     = make_ushort4(f2bf(p0[0]),f2bf(p0[1]),f2bf(p0[2]),f2bf(p0[3]));
  *(ushort4*)(pb + base + tid*8 + 4) = make_ushort4(f2bf(p1[0]),f2bf(p1[1]),f2bf(p1[2]),f2bf(p1[3]));
}

extern "C" void kernel_launch(void* const* d_in, const int* in_sizes, int n_in,
                              void* d_out, int out_size, void* d_ws, size_t ws_size,
                              hipStream_t stream){
  (void)in_sizes; (void)n_in; (void)out_size; (void)ws_size;
  const float* values = (const float*)d_in[0];   // [Tv,B,V]
  const float* keys   = (const float*)d_in[2];   // [B,Tk,K]
  const float* w      = (const float*)d_in[3];   // [K,V]

  float* attn = (float*)d_out;                       // [B,Tk,Tv]
  float* outp = (float*)d_out + (long)NB_*TK_*TV_;   // [B,Tk,V]

  char* ws = (char*)d_ws;
  const long MB = 1024L*1024L;
  ushort* khi  = (ushort*)(ws);              // 64MB keys-hi   (reused: v2hi, vbt)
  ushort* klo  = (ushort*)(ws + 64*MB);      // 64MB keys-lo   (reused: v2lo)
  ushort* plhi = (ushort*)(ws + 128*MB);     // 64MB pl-hi     (reused: adb[0:half])
  ushort* pllo = (ushort*)(ws + 192*MB);     // 64MB pl-lo     (reused: adb[half:])
  ushort* wth  = (ushort*)(ws + 256*MB);     // 2MB  wT-hi
  ushort* wtl  = (ushort*)(ws + 258*MB);     // 2MB  wT-lo
  ushort* v2h  = khi;                        // [B,Tv,V] hi
  ushort* v2l  = klo;                        // [B,Tv,V] lo
  ushort* adb  = plhi;                       // [B,Tk,Tv] bf16 (128MB contiguous)
  ushort* vbt  = khi;                        // [B,V,Tv] bf16

  // 1) split keys -> bf16 pair
  split_pair_k<<<2048,256,0,stream>>>(keys, khi, klo, (long)NB_*TK_*NK_/4);
  // 2) transpose+split w -> wT pair
  wtrans_k<<<dim3(32,32),dim3(32,8),0,stream>>>(w, wth, wtl);
  // 3) GEMM1 (bf16x3): pl = keys * w   -> bf16 pair [B,Tk,V]
  gemm_bt_k<3,1><<<dim3(NV_/128, TK_/128, NB_),256,0,stream>>>(
      khi, klo, wth, wtl, nullptr, plhi, pllo,
      NV_, NK_, (long)TK_*NK_, 0L, (long)TK_*NV_);
  // 4) build v2 pair [B,Tv,V] (reuses keys-pair space; stream-ordered after GEMM1)
  v2_build_k<<<2048,256,0,stream>>>(values, v2h, v2l);
  // 5) GEMM2 (bf16x3): logits = pl * v2^T -> fp32 into d_out attn region
  gemm_bt_k<3,0><<<dim3(TV_/128, TK_/128, NB_),256,0,stream>>>(
      plhi, pllo, v2h, v2l, attn, nullptr, nullptr,
      TV_, NV_, (long)TK_*NV_, (long)TV_*NV_, (long)TK_*TV_);
  // 6) softmax in place + bf16 copy (adb reuses pl space)
  softmax_k<<<NB_*TK_,256,0,stream>>>(attn, adb);
  // 7) build vbt [B,V,Tv] (reuses v2 space)
  vbt_build_k<<<dim3(TV_/32, NV_/32, NB_),dim3(32,8),0,stream>>>(values, vbt);
  // 8) GEMM3 (plain bf16): out = attn * values_bt -> fp32
  gemm_bt_k<1,0><<<dim3(NV_/128, TK_/128, NB_),256,0,stream>>>(
      adb, nullptr, vbt, nullptr, outp, nullptr, nullptr,
      NV_, TV_, (long)TK_*TV_, (long)NV_*TV_, (long)TK_*NV_);
}

// Round 3
// 822.762 us; speedup vs baseline: 1.3353x; 1.3353x over previous
//
#include <hip/hip_runtime.h>

// Problem constants (from reference)
#define TV_ 2048
#define NB_ 16
#define NV_ 1024
#define TK_ 2048
#define NK_ 1024

typedef float    f32x4 __attribute__((ext_vector_type(4)));
typedef float    fl4   __attribute__((ext_vector_type(4)));
typedef _Float16 hfx8  __attribute__((ext_vector_type(8)));

static __device__ __forceinline__ ushort f2h(float f){
  _Float16 h = (_Float16)f;               // RN-even
  return __builtin_bit_cast(ushort, h);
}

// ---------------- elementwise convert: fp32 -> fp16 ----------------
__global__ __launch_bounds__(256) void cvt_h_k(const float* __restrict__ x,
                                               ushort* __restrict__ y, long n4){
  long i = (long)blockIdx.x*256 + threadIdx.x;
  const long stride = (long)gridDim.x*256;
  for (; i < n4; i += stride){
    fl4 v = ((const fl4*)x)[i];
    ((ushort4*)y)[i] = make_ushort4(f2h(v[0]), f2h(v[1]), f2h(v[2]), f2h(v[3]));
  }
}

// ---------------- w [K,V] -> wT [V,K] fp16 ----------------
__global__ void wtrans_k(const float* __restrict__ w, ushort* __restrict__ wT){
  __shared__ float t[32][33];
  const int tx = threadIdx.x, ty = threadIdx.y;       // 32 x 8
  const int k0 = blockIdx.x*32, v0 = blockIdx.y*32;
#pragma unroll
  for (int r=0;r<4;++r) t[ty+8*r][tx] = w[(long)(k0+ty+8*r)*NV_ + v0+tx];
  __syncthreads();
#pragma unroll
  for (int r=0;r<4;++r)
    wT[(long)(v0+ty+8*r)*NK_ + k0+tx] = f2h(t[tx][ty+8*r]);
}

// ------------- values [Tv,B,V] -> v2 [B,Tv,V] fp16 (pure permutation) -------------
__global__ __launch_bounds__(256) void v2_build_k(const float* __restrict__ vals,
                                                  ushort* __restrict__ out){
  const long n4 = (long)NB_*TV_*NV_/4;
  long i = (long)blockIdx.x*256 + threadIdx.x;
  const long stride = (long)gridDim.x*256;
  for (; i < n4; i += stride){
    const long o = i << 2;
    const int b = (int)(o >> 21);              // / (Tv*V) = 2^21
    const int s = (int)((o >> 10) & (TV_-1));
    const int v = (int)(o & (NV_-1));
    fl4 val = *(const fl4*)(vals + ((long)s*NB_ + b)*NV_ + v);
    *(ushort4*)(out + o) = make_ushort4(f2h(val[0]), f2h(val[1]), f2h(val[2]), f2h(val[3]));
  }
}

// ------------- values [Tv,B,V] -> vbt [B,V,Tv] fp16, tiled transpose -------------
__global__ void vbt_build_k(const float* __restrict__ vals, ushort* __restrict__ out){
  __shared__ float t[32][33];
  const int tx = threadIdx.x, ty = threadIdx.y;       // 32 x 8
  const int s0 = blockIdx.x*32, v0 = blockIdx.y*32, b = blockIdx.z;
#pragma unroll
  for (int r=0;r<4;++r)
    t[ty+8*r][tx] = vals[((long)(s0+ty+8*r)*NB_ + b)*NV_ + v0+tx];
  __syncthreads();
#pragma unroll
  for (int r=0;r<4;++r)
    out[((long)b*NV_ + v0+ty+8*r)*TV_ + s0+tx] = f2h(t[tx][ty+8*r]);
}

// ---------------- GEMM: C[M,N] (+batch) = A[M,K] * BT[N,K]^T, fp16 single-pass ----------------
// MFMA 16x16x32_f16, 128x128 tile, BK=64, 4 waves, global_load_lds staging,
// XOR swizzle (16B slot ^ (row&7)) applied on the *source* address (linear LDS dest),
// unwound at ds_read time.
static __device__ __forceinline__ void stage_tile(const ushort* __restrict__ src, int ldk,
                                                  ushort* dst, int w, int lane){
#pragma unroll
  for (int c=0;c<4;++c){
    const int chunk0 = (w<<8) + (c<<6);       // wave-uniform 16B-chunk base
    const int idx = chunk0 + lane;            // this lane's chunk
    const int row = idx >> 3;                 // 8 chunks (128B) per row
    const int sl  = idx & 7;
    const ushort* g = src + (long)row*ldk + ((sl ^ (row & 7)) << 3);
    __builtin_amdgcn_global_load_lds((const __attribute__((address_space(1))) unsigned int*)g,
                                     (__attribute__((address_space(3))) unsigned int*)(dst + (long)chunk0*8),
                                     16, 0, 0);
  }
}

static __device__ __forceinline__ hfx8 ldfrag(const ushort* base, int r, int q){
  const int off = r*128 + (((q ^ (r & 7)) & 7) << 4);
  return *(const hfx8*)((const char*)base + off);
}

template<int OUTF16>
__global__ __launch_bounds__(256)
void gemm_f16_k(const ushort* __restrict__ A, const ushort* __restrict__ BT,
                float* __restrict__ C, ushort* __restrict__ Ch,
                int N, int K, long sA, long sB, long sC)
{
  __shared__ __align__(16) ushort sA_[128*64];
  __shared__ __align__(16) ushort sB_[128*64];

  const int tid  = threadIdx.x;
  const int lane = tid & 63;
  const int w    = tid >> 6;
  const int bz   = blockIdx.z;
  const int m0   = blockIdx.y * 128;
  const int n0   = blockIdx.x * 128;

  const ushort* Ap = A  + (long)bz*sA + (long)m0*K;
  const ushort* Bp = BT + (long)bz*sB + (long)n0*K;

  f32x4 acc[4][4];
#pragma unroll
  for (int i=0;i<4;++i)
#pragma unroll
    for (int j=0;j<4;++j) acc[i][j] = (f32x4){0.f,0.f,0.f,0.f};

  const int wm = (w>>1)*64, wn = (w&1)*64;
  const int lm = lane & 15, lq = lane >> 4;

  for (int k0=0; k0<K; k0+=64){
    __syncthreads();                 // protect LDS from previous iter's readers
    stage_tile(Ap + k0, K, sA_, w, lane);
    stage_tile(Bp + k0, K, sB_, w, lane);
    __syncthreads();                 // compiler drains vmcnt(0) before barrier
#pragma unroll
    for (int kk=0; kk<2; ++kk){
      hfx8 a[4], b[4];
#pragma unroll
      for (int i=0;i<4;++i) a[i] = ldfrag(sA_, wm + i*16 + lm, lq + kk*4);
#pragma unroll
      for (int j=0;j<4;++j) b[j] = ldfrag(sB_, wn + j*16 + lm, lq + kk*4);
#pragma unroll
      for (int i=0;i<4;++i)
#pragma unroll
        for (int j=0;j<4;++j)
          acc[i][j] = __builtin_amdgcn_mfma_f32_16x16x32_f16(a[i], b[j], acc[i][j], 0,0,0);
    }
  }

  const long cb = (long)bz*sC;
#pragma unroll
  for (int i=0;i<4;++i)
#pragma unroll
    for (int j=0;j<4;++j)
#pragma unroll
      for (int g=0; g<4; ++g){
        const int gm = m0 + wm + i*16 + lq*4 + g;   // C/D: row = 4*(lane>>4)+reg
        const int gn = n0 + wn + j*16 + lm;         //      col = lane&15
        const long o = cb + (long)gm*N + gn;
        if constexpr (OUTF16) Ch[o] = f2h(acc[i][j][g]);
        else                  C[o]  = acc[i][j][g];
      }
}

// ---------------- row softmax over Tv, in-place fp32 + fp16 copy ----------------
__global__ __launch_bounds__(256) void softmax_k(float* __restrict__ lg, ushort* __restrict__ pb){
  const long base = (long)blockIdx.x * TV_;
  const int tid = threadIdx.x;
  const int lane = tid & 63, w = tid >> 6;
  float x[8];
  fl4 a = *(const fl4*)(lg + base + tid*8);
  fl4 b = *(const fl4*)(lg + base + tid*8 + 4);
  x[0]=a[0];x[1]=a[1];x[2]=a[2];x[3]=a[3];x[4]=b[0];x[5]=b[1];x[6]=b[2];x[7]=b[3];
  float m = x[0];
#pragma unroll
  for (int j=1;j<8;++j) m = fmaxf(m, x[j]);
#pragma unroll
  for (int off=32; off; off>>=1) m = fmaxf(m, __shfl_xor(m, off));
  __shared__ float rm[4], rs[4];
  if (lane==0) rm[w]=m;
  __syncthreads();
  m = fmaxf(fmaxf(rm[0],rm[1]), fmaxf(rm[2],rm[3]));
  float s = 0.f;
#pragma unroll
  for (int j=0;j<8;++j){ x[j] = __expf(x[j]-m); s += x[j]; }
#pragma unroll
  for (int off=32; off; off>>=1) s += __shfl_xor(s, off);
  if (lane==0) rs[w]=s;
  __syncthreads();
  s = rs[0]+rs[1]+rs[2]+rs[3];
  const float inv = 1.f/s;
  fl4 p0 = {x[0]*inv, x[1]*inv, x[2]*inv, x[3]*inv};
  fl4 p1 = {x[4]*inv, x[5]*inv, x[6]*inv, x[7]*inv};
  *(fl4*)(lg + base + tid*8)     = p0;
  *(fl4*)(lg + base + tid*8 + 4) = p1;
  *(ushort4*)(pb + base + tid*8)     = make_ushort4(f2h(p0[0]),f2h(p0[1]),f2h(p0[2]),f2h(p0[3]));
  *(ushort4*)(pb + base + tid*8 + 4) = make_ushort4(f2h(p1[0]),f2h(p1[1]),f2h(p1[2]),f2h(p1[3]));
}

extern "C" void kernel_launch(void* const* d_in, const int* in_sizes, int n_in,
                              void* d_out, int out_size, void* d_ws, size_t ws_size,
                              hipStream_t stream){
  (void)in_sizes; (void)n_in; (void)out_size; (void)ws_size;
  const float* values = (const float*)d_in[0];   // [Tv,B,V]
  const float* keys   = (const float*)d_in[2];   // [B,Tk,K]
  const float* w      = (const float*)d_in[3];   // [K,V]

  float* attn = (float*)d_out;                       // [B,Tk,Tv]
  float* outp = (float*)d_out + (long)NB_*TK_*TV_;   // [B,Tk,V]

  char* ws = (char*)d_ws;
  const long MB = 1024L*1024L;
  ushort* kh  = (ushort*)(ws);               // 64MB keys fp16  (reused: v2, then vbt)
  ushort* plh = (ushort*)(ws + 128*MB);      // 64MB pl fp16
  ushort* adb = (ushort*)(ws + 128*MB);      // 128MB attn fp16 (overlays pl after GEMM2)
  ushort* wth = (ushort*)(ws + 256*MB);      // 2MB  wT fp16
  ushort* v2  = kh;                          // [B,Tv,V] fp16
  ushort* vbt = kh;                          // [B,V,Tv] fp16

  // 1) keys -> fp16
  cvt_h_k<<<2048,256,0,stream>>>(keys, kh, (long)NB_*TK_*NK_/4);
  // 2) w -> wT fp16
  wtrans_k<<<dim3(32,32),dim3(32,8),0,stream>>>(w, wth);
  // 3) GEMM1: pl = keys * w -> fp16 [B,Tk,V]
  gemm_f16_k<1><<<dim3(NV_/128, TK_/128, NB_),256,0,stream>>>(
      kh, wth, nullptr, plh, NV_, NK_, (long)TK_*NK_, 0L, (long)TK_*NV_);
  // 4) v2 [B,Tv,V] fp16 (reuses keys space; stream-ordered after GEMM1)
  v2_build_k<<<2048,256,0,stream>>>(values, v2);
  // 5) GEMM2: logits = pl * v2^T -> fp32 into d_out attn region
  gemm_f16_k<0><<<dim3(TV_/128, TK_/128, NB_),256,0,stream>>>(
      plh, v2, attn, nullptr, TV_, NV_, (long)TK_*NV_, (long)TV_*NV_, (long)TK_*TV_);
  // 6) softmax in place + fp16 copy (adb overlays pl space)
  softmax_k<<<NB_*TK_,256,0,stream>>>(attn, adb);
  // 7) vbt [B,V,Tv] fp16 (reuses v2 space)
  vbt_build_k<<<dim3(TV_/32, NV_/32, NB_),dim3(32,8),0,stream>>>(values, vbt);
  // 8) GEMM3: out = attn * vbt^T -> fp32
  gemm_f16_k<0><<<dim3(NV_/128, TK_/128, NB_),256,0,stream>>>(
      adb, vbt, outp, nullptr, NV_, TV_, (long)TK_*TV_, (long)NV_*TV_, (long)TK_*NV_);
}

// Round 5
// 608.524 us; speedup vs baseline: 1.8054x; 1.3521x over previous
//
#include <hip/hip_runtime.h>

// Problem constants (from reference)
#define TV_ 2048
#define NB_ 16
#define NV_ 1024
#define TK_ 2048
#define NK_ 1024

typedef float    f32x4 __attribute__((ext_vector_type(4)));
typedef float    fl4   __attribute__((ext_vector_type(4)));
typedef _Float16 hfx8  __attribute__((ext_vector_type(8)));

static __device__ __forceinline__ ushort f2h(float f){
  _Float16 h = (_Float16)f;               // RN-even
  return __builtin_bit_cast(ushort, h);
}

// ---------------- elementwise convert: fp32 -> fp16 ----------------
__global__ __launch_bounds__(256) void cvt_h_k(const float* __restrict__ x,
                                               ushort* __restrict__ y, long n4){
  long i = (long)blockIdx.x*256 + threadIdx.x;
  const long stride = (long)gridDim.x*256;
  for (; i < n4; i += stride){
    fl4 v = ((const fl4*)x)[i];
    ((ushort4*)y)[i] = make_ushort4(f2h(v[0]), f2h(v[1]), f2h(v[2]), f2h(v[3]));
  }
}

// ---------------- w [K,V] -> wT [V,K] fp16 ----------------
__global__ void wtrans_k(const float* __restrict__ w, ushort* __restrict__ wT){
  __shared__ float t[32][33];
  const int tx = threadIdx.x, ty = threadIdx.y;       // 32 x 8
  const int k0 = blockIdx.x*32, v0 = blockIdx.y*32;
#pragma unroll
  for (int r=0;r<4;++r) t[ty+8*r][tx] = w[(long)(k0+ty+8*r)*NV_ + v0+tx];
  __syncthreads();
#pragma unroll
  for (int r=0;r<4;++r)
    wT[(long)(v0+ty+8*r)*NK_ + k0+tx] = f2h(t[tx][ty+8*r]);
}

// ------- values [Tv,B,V] -> v2 [B,Tv,V] fp16 AND vbt [B,V,Tv] fp16, one read -------
__global__ void vboth_k(const float* __restrict__ vals,
                        ushort* __restrict__ v2, ushort* __restrict__ vbt){
  __shared__ float t[32][33];
  const int tx = threadIdx.x, ty = threadIdx.y;       // 32 x 8
  const int s0 = blockIdx.x*32, v0 = blockIdx.y*32, b = blockIdx.z;
#pragma unroll
  for (int r=0;r<4;++r){
    float x = vals[((long)(s0+ty+8*r)*NB_ + b)*NV_ + v0+tx];
    t[ty+8*r][tx] = x;
    v2[((long)b*TV_ + s0+ty+8*r)*NV_ + v0+tx] = f2h(x);
  }
  __syncthreads();
#pragma unroll
  for (int r=0;r<4;++r)
    vbt[((long)b*NV_ + v0+ty+8*r)*TV_ + s0+tx] = f2h(t[tx][ty+8*r]);
}

// =======================================================================
// 256x256 8-phase GEMM: C[M,N](+batch) = A[M,K] * BT[N,K]^T, fp16 MFMA.
// 512 thr = 8 waves (2M x 4N), per-wave 128x64 out. BK=64, dbuf LDS 128KiB.
// Half-tile = [128][64] fp16 = 16KB, staged by 2 global_load_lds per thread,
// source-side XOR swizzle (16B slot ^ (row&7)) -> conflict-free ds_read_b128.
// Counted vmcnt(4) at phases 4/8 only (T4); setprio around MFMA (T5).
// Staging dependency pattern: KTILE on tile t stages {A1,B1}(t+1) at S0/S1
// and {B0,A0}(t+2) at S2/S3. R3 BUG (fixed): the peeled tile NT-2 KTILE must
// still run S0/S1 for tile NT-1, else the last tile reads stale half-1 data.
// =======================================================================
static __device__ __forceinline__ hfx8 ldfrag(const ushort* base, int r, int q){
  const int off = r*128 + (((q ^ (r & 7)) & 7) << 4);
  return *(const hfx8*)((const char*)base + off);
}

#define SAOFF(b,h) (((b)*2+(h))*8192)
#define SBOFF(b,h) (32768 + ((b)*2+(h))*8192)

#define STAGE(Xp, hb, t, ldsoff) do { \
  _Pragma("unroll") \
  for (int c_=0;c_<2;++c_) \
    __builtin_amdgcn_global_load_lds( \
      (const __attribute__((address_space(1))) unsigned*)((Xp) + (long)(hb)*128*K + (long)(t)*64 + soff[c_]), \
      (__attribute__((address_space(3))) unsigned*)(lds + (ldsoff) + chunk0[c_]*8), 16, 0, 0); \
} while(0)

#define VM4 asm volatile("s_waitcnt vmcnt(4)" ::: "memory")
#define VM0 asm volatile("s_waitcnt vmcnt(0)" ::: "memory")
#define NOPS (void)0

#define BARR() do { __builtin_amdgcn_s_barrier(); __builtin_amdgcn_sched_barrier(0); } while(0)

#define MFMA_SET(IB, JB, BREG) \
  _Pragma("unroll") for (int kk=0;kk<2;++kk) \
  _Pragma("unroll") for (int i=0;i<4;++i) \
  _Pragma("unroll") for (int j=0;j<2;++j) \
    acc[(IB)+i][(JB)+j] = __builtin_amdgcn_mfma_f32_16x16x32_f16(aR[i][kk], BREG[j][kk], acc[(IB)+i][(JB)+j], 0,0,0)

// One K-tile = 4 phases. S0..S3: stage statements; EW: end wait (vmcnt) at PH3.
#define KTILE(BUF, S0, S1, S2, S3, EW) do { \
  const ushort* sa_ = lds + SAOFF(BUF, wr); \
  const ushort* sb_ = lds + SBOFF(BUF, (wc>>1)); \
  const int brow_ = (wc&1)*64; \
  /* PH0: read a[0..3], b01 ; mfma acc[0..3][0..1] */ \
  _Pragma("unroll") for (int i=0;i<4;++i) _Pragma("unroll") for (int kk=0;kk<2;++kk) \
    aR[i][kk] = ldfrag(sa_, i*16+lm, lq+kk*4); \
  _Pragma("unroll") for (int j=0;j<2;++j) _Pragma("unroll") for (int kk=0;kk<2;++kk) \
    b01[j][kk] = ldfrag(sb_, brow_ + j*16 + lm, lq+kk*4); \
  S0; \
  BARR(); \
  __builtin_amdgcn_s_setprio(1); \
  MFMA_SET(0, 0, b01); \
  __builtin_amdgcn_s_setprio(0); \
  BARR(); \
  /* PH1: read b23 ; mfma acc[0..3][2..3] */ \
  _Pragma("unroll") for (int j=0;j<2;++j) _Pragma("unroll") for (int kk=0;kk<2;++kk) \
    b23[j][kk] = ldfrag(sb_, brow_ + (2+j)*16 + lm, lq+kk*4); \
  S1; \
  BARR(); \
  __builtin_amdgcn_s_setprio(1); \
  MFMA_SET(0, 2, b23); \
  __builtin_amdgcn_s_setprio(0); \
  BARR(); \
  /* PH2: read a[4..7] ; mfma acc[4..7][2..3] */ \
  _Pragma("unroll") for (int i=0;i<4;++i) _Pragma("unroll") for (int kk=0;kk<2;++kk) \
    aR[i][kk] = ldfrag(sa_, (4+i)*16+lm, lq+kk*4); \
  S2; \
  BARR(); \
  __builtin_amdgcn_s_setprio(1); \
  MFMA_SET(4, 2, b23); \
  __builtin_amdgcn_s_setprio(0); \
  BARR(); \
  /* PH3: (b01 cached) ; mfma acc[4..7][0..1] */ \
  S3; \
  BARR(); \
  __builtin_amdgcn_s_setprio(1); \
  MFMA_SET(4, 0, b01); \
  __builtin_amdgcn_s_setprio(0); \
  EW; \
  BARR(); \
} while(0)

template<int OUTF16>
__global__ __launch_bounds__(512, 2)
void gemm8_k(const ushort* __restrict__ A, const ushort* __restrict__ BT,
             float* __restrict__ C, ushort* __restrict__ Ch,
             int N, int K, long sA, long sB, long sC)
{
  extern __shared__ ushort lds[];   // 131072 B: A halves [0,32K), B halves [32K,64K) (ushort idx)

  const int tid  = threadIdx.x;
  const int lane = tid & 63;
  const int w    = tid >> 6;
  const int wr   = w >> 2;          // 0..1  (M half)
  const int wc   = w & 3;           // 0..3  (N quarter)
  const int lm   = lane & 15, lq = lane >> 4;
  const int bz   = blockIdx.z;
  const long m0  = (long)blockIdx.y * 256;
  const long n0  = (long)blockIdx.x * 256;

  const ushort* Ap = A  + (long)bz*sA + m0*K;
  const ushort* Bp = BT + (long)bz*sB + n0*K;

  // per-thread stage source offsets (2 chunks of one [128][64] half-tile)
  int chunk0[2], soff[2];
#pragma unroll
  for (int c=0;c<2;++c){
    chunk0[c] = (w<<7) + (c<<6);
    const int idx = chunk0[c] + lane;
    const int row = idx >> 3, sl = idx & 7;
    soff[c] = row*K + ((sl ^ (row & 7)) << 3);
  }

  f32x4 acc[8][4];
#pragma unroll
  for (int i=0;i<8;++i)
#pragma unroll
    for (int j=0;j<4;++j) acc[i][j] = (f32x4){0.f,0.f,0.f,0.f};

  hfx8 aR[4][2], b01[2][2], b23[2][2];

  const int NT = K >> 6;            // K-tiles (>=4, even, for all our shapes)

  // Prologue: tile0 fully + B0/A0 of tile1 in flight
  STAGE(Ap, 0, 0, SAOFF(0,0));
  STAGE(Ap, 1, 0, SAOFF(0,1));
  STAGE(Bp, 0, 0, SBOFF(0,0));
  STAGE(Bp, 1, 0, SBOFF(0,1));
  STAGE(Bp, 0, 1, SBOFF(1,0));
  STAGE(Ap, 0, 1, SAOFF(1,0));
  VM4;                              // tile0's 8 loads done; 4 newest may fly
  BARR();

  for (int u=0; u <= NT-4; u+=2){
    // tile u (buf0): stage A1(u+1), B1(u+1), B0(u+2), A0(u+2)
    KTILE(0,
          STAGE(Ap, 1, u+1, SAOFF(1,1)),
          STAGE(Bp, 1, u+1, SBOFF(1,1)),
          STAGE(Bp, 0, u+2, SBOFF(0,0)),
          STAGE(Ap, 0, u+2, SAOFF(0,0)),
          VM4);
    // tile u+1 (buf1): stage A1(u+2), B1(u+2), B0(u+3), A0(u+3)
    KTILE(1,
          STAGE(Ap, 1, u+2, SAOFF(0,1)),
          STAGE(Bp, 1, u+2, SBOFF(0,1)),
          STAGE(Bp, 0, u+3, SBOFF(1,0)),
          STAGE(Ap, 0, u+3, SAOFF(1,0)),
          VM4);
  }
  // Peeled tile NT-2 (buf0): MUST still stage A1/B1 of tile NT-1 (R3 bugfix),
  // then drain everything (VM0) so tile NT-1's 4 half-tiles are all landed.
  KTILE(0,
        STAGE(Ap, 1, NT-1, SAOFF(1,1)),
        STAGE(Bp, 1, NT-1, SBOFF(1,1)),
        NOPS, NOPS, VM0);
  // Peeled tile NT-1 (buf1): no staging
  KTILE(1, NOPS, NOPS, NOPS, NOPS, NOPS);

  // Epilogue C-write (same per-element mapping/conversion as before)
  const long cb = (long)bz*sC;
#pragma unroll
  for (int i=0;i<8;++i)
#pragma unroll
    for (int j=0;j<4;++j)
#pragma unroll
      for (int g=0; g<4; ++g){
        const long gm = m0 + wr*128 + i*16 + lq*4 + g;   // C/D: row = 4*(lane>>4)+reg
        const long gn = n0 + wc*64  + j*16 + lm;         //      col = lane&15
        const long o = cb + gm*N + gn;
        if constexpr (OUTF16) Ch[o] = f2h(acc[i][j][g]);
        else                  C[o]  = acc[i][j][g];
      }
}

// ---------------- row softmax over Tv, in-place fp32 + fp16 copy ----------------
__global__ __launch_bounds__(256) void softmax_k(float* __restrict__ lg, ushort* __restrict__ pb){
  const long base = (long)blockIdx.x * TV_;
  const int tid = threadIdx.x;
  const int lane = tid & 63, w = tid >> 6;
  float x[8];
  fl4 a = *(const fl4*)(lg + base + tid*8);
  fl4 b = *(const fl4*)(lg + base + tid*8 + 4);
  x[0]=a[0];x[1]=a[1];x[2]=a[2];x[3]=a[3];x[4]=b[0];x[5]=b[1];x[6]=b[2];x[7]=b[3];
  float m = x[0];
#pragma unroll
  for (int j=1;j<8;++j) m = fmaxf(m, x[j]);
#pragma unroll
  for (int off=32; off; off>>=1) m = fmaxf(m, __shfl_xor(m, off));
  __shared__ float rm[4], rs[4];
  if (lane==0) rm[w]=m;
  __syncthreads();
  m = fmaxf(fmaxf(rm[0],rm[1]), fmaxf(rm[2],rm[3]));
  float s = 0.f;
#pragma unroll
  for (int j=0;j<8;++j){ x[j] = __expf(x[j]-m); s += x[j]; }
#pragma unroll
  for (int off=32; off; off>>=1) s += __shfl_xor(s, off);
  if (lane==0) rs[w]=s;
  __syncthreads();
  s = rs[0]+rs[1]+rs[2]+rs[3];
  const float inv = 1.f/s;
  fl4 p0 = {x[0]*inv, x[1]*inv, x[2]*inv, x[3]*inv};
  fl4 p1 = {x[4]*inv, x[5]*inv, x[6]*inv, x[7]*inv};
  *(fl4*)(lg + base + tid*8)     = p0;
  *(fl4*)(lg + base + tid*8 + 4) = p1;
  *(ushort4*)(pb + base + tid*8)     = make_ushort4(f2h(p0[0]),f2h(p0[1]),f2h(p0[2]),f2h(p0[3]));
  *(ushort4*)(pb + base + tid*8 + 4) = make_ushort4(f2h(p1[0]),f2h(p1[1]),f2h(p1[2]),f2h(p1[3]));
}

extern "C" void kernel_launch(void* const* d_in, const int* in_sizes, int n_in,
                              void* d_out, int out_size, void* d_ws, size_t ws_size,
                              hipStream_t stream){
  (void)in_sizes; (void)n_in; (void)out_size; (void)ws_size;
  const float* values = (const float*)d_in[0];   // [Tv,B,V]
  const float* keys   = (const float*)d_in[2];   // [B,Tk,K]
  const float* w      = (const float*)d_in[3];   // [K,V]

  float* attn = (float*)d_out;                       // [B,Tk,Tv]
  float* outp = (float*)d_out + (long)NB_*TK_*TV_;   // [B,Tk,V]

  char* ws = (char*)d_ws;
  const long MB = 1024L*1024L;
  ushort* kh  = (ushort*)(ws);               // 64MB keys fp16 (reused: v2)
  ushort* vbt = (ushort*)(ws + 64*MB);       // 64MB vbt [B,V,Tv] fp16
  ushort* plh = (ushort*)(ws + 128*MB);      // 64MB pl fp16
  ushort* adb = (ushort*)(ws + 128*MB);      // 128MB attn fp16 (overlays pl after GEMM2)
  ushort* wth = (ushort*)(ws + 256*MB);      // 2MB  wT fp16
  ushort* v2  = kh;                          // [B,Tv,V] fp16

  const size_t LDSB = 131072;

  // 1) keys -> fp16
  cvt_h_k<<<2048,256,0,stream>>>(keys, kh, (long)NB_*TK_*NK_/4);
  // 2) w -> wT fp16
  wtrans_k<<<dim3(32,32),dim3(32,8),0,stream>>>(w, wth);
  // 3) GEMM1: pl = keys * w -> fp16 [B,Tk,V]
  gemm8_k<1><<<dim3(NV_/256, TK_/256, NB_),512,LDSB,stream>>>(
      kh, wth, nullptr, plh, NV_, NK_, (long)TK_*NK_, 0L, (long)TK_*NV_);
  // 4) v2 [B,Tv,V] + vbt [B,V,Tv] fp16 in one pass (v2 reuses keys space; after GEMM1)
  vboth_k<<<dim3(TV_/32, NV_/32, NB_),dim3(32,8),0,stream>>>(values, v2, vbt);
  // 5) GEMM2: logits = pl * v2^T -> fp32 into d_out attn region
  gemm8_k<0><<<dim3(TV_/256, TK_/256, NB_),512,LDSB,stream>>>(
      plh, v2, attn, nullptr, TV_, NV_, (long)TK_*NV_, (long)TV_*NV_, (long)TK_*TV_);
  // 6) softmax in place + fp16 copy (adb overlays pl space)
  softmax_k<<<NB_*TK_,256,0,stream>>>(attn, adb);
  // 7) GEMM3: out = attn * vbt^T -> fp32
  gemm8_k<0><<<dim3(NV_/256, TK_/256, NB_),512,LDSB,stream>>>(
      adb, vbt, outp, nullptr, NV_, TV_, (long)TK_*TV_, (long)NV_*TV_, (long)TK_*NV_);
}